// Round 18
// baseline (203.088 us; speedup 1.0000x reference)
//
#include <hip/hip_runtime.h>
#include <hip/hip_bf16.h>

typedef __attribute__((ext_vector_type(8))) short short8;
typedef __attribute__((ext_vector_type(4))) float f32x4;
typedef __attribute__((ext_vector_type(4))) int   i32x4;
typedef __attribute__((ext_vector_type(4))) unsigned short us4;

#define NTOP 1000
#define KC   256
#define MROWS 40000
#define MBLK  64
// Workspace: colsum 8K | Bp 512K | Cb 5.12M | Af 20.48M
#define OFF_BP  8192
#define OFF_CB  532480
#define OFF_AF  5652480
#define WS_FULL 26132480
#define WS_CB   5652480

static __device__ __forceinline__ unsigned short f2bf(float x) {
    union { float f; unsigned u; } v; v.f = x;
    unsigned r = (v.u + 0x7FFFu + ((v.u >> 16) & 1u)) >> 16;
    return (unsigned short)r;
}

// Kernel 1: colsum[j] += sum over an 8-row slab of nw.
__global__ void k_prep(const float* __restrict__ nw,
                       float* __restrict__ colsum) {
    int j  = blockIdx.x * 256 + threadIdx.x;
    int i0 = blockIdx.y * 8;
    if (j < NTOP) {
        float s = 0.f;
        int iend = min(i0 + 8, NTOP);
        for (int i = i0; i < iend; ++i) s += nw[(size_t)i * NTOP + j];
        atomicAdd(colsum + j, s);
    }
}

// Kernel 2: build B' in MFMA-fragment order (unchanged).
__global__ void k_vj(const float* __restrict__ V,
                     const float* __restrict__ noise,
                     const float* __restrict__ colsum,
                     unsigned short* __restrict__ Bp) {
    int t  = blockIdx.x * 256 + threadIdx.x;
    int nt = t >> 9;
    int s  = (t >> 6) & 7;
    int l  = t & 63;
    int lm = l & 15, lq = l >> 4;
    int n  = nt * 16 + lm;
    int k0 = s * 32 + lq * 8;
    union { short8 v; unsigned short us[8]; } pk;
    if (n < NTOP) {
        float cs = colsum[n];
        #pragma unroll
        for (int j = 0; j < 8; ++j) {
            int idx = n * KC + k0 + j;
            pk.us[j] = f2bf(V[idx] * cs + 0.1f * noise[idx]);
        }
    } else {
        #pragma unroll
        for (int j = 0; j < 8; ++j) pk.us[j] = 0;
    }
    reinterpret_cast<short8*>(Bp)[t] = pk.v;
}

// Kernel 2b: compress C -> row-major bitmask Cb[m][n/32] (5 MB). Proven.
__global__ __launch_bounds__(256) void k_cmask(const int* __restrict__ C,
                                               unsigned* __restrict__ Cb) {
    const int idx = blockIdx.x * 256 + threadIdx.x;
    const int m = idx >> 5, w = idx & 31;
    const int* p = C + (size_t)m * NTOP + w * 32;
    const int nbase = w * 32;
    unsigned word = 0;
    if (nbase + 32 <= NTOP) {
        #pragma unroll
        for (int j = 0; j < 32; j += 4) {
            i32x4 c4 = *reinterpret_cast<const i32x4*>(p + j);
            word |= (unsigned)(c4.x == 1) << (j + 0);
            word |= (unsigned)(c4.y == 1) << (j + 1);
            word |= (unsigned)(c4.z == 1) << (j + 2);
            word |= (unsigned)(c4.w == 1) << (j + 3);
        }
    } else {
        for (int j = 0; j < NTOP - nbase; ++j)
            word |= (unsigned)(p[j] == 1) << j;
    }
    Cb[idx] = word;
}

// Kernel 2c: U_emb -> Af fragments in MFMA order, bf16 (20.48 MB).
// Af[(mt*8 + s)*64 + l] (short8) = U_emb[mt*16+(l&15), s*32+(l>>4)*8 + j]
// Streams U (205 MB) ONCE at full BW; removes the A-build from k_main.
__global__ __launch_bounds__(256) void k_uemb(
    const float* __restrict__ U, const float* __restrict__ w5,
    const float* __restrict__ b1, short8* __restrict__ Af)
{
    const int o  = blockIdx.x * 256 + threadIdx.x;   // < 2500*8*64 = 1,280,000
    const int l  = o & 63;
    const int s  = (o >> 6) & 7;
    const int mt = o >> 9;
    const int m  = (mt << 4) + (l & 15);
    const int k0 = (s << 5) + ((l >> 4) << 3);
    const float w0 = w5[0], w1 = w5[1], w2 = w5[2], w3 = w5[3], w4 = w5[4];
    const float bb = b1[0];

    const f32x4* up4 = reinterpret_cast<const f32x4*>(U + ((size_t)m * KC + k0) * 5);
    float u[40];
    #pragma unroll
    for (int i = 0; i < 10; ++i) {
        f32x4 t = up4[i];
        u[i*4+0] = t.x; u[i*4+1] = t.y; u[i*4+2] = t.z; u[i*4+3] = t.w;
    }
    union { short8 v; unsigned short us[8]; } pk;
    #pragma unroll
    for (int j = 0; j < 8; ++j) {
        float e = u[j*5+0]*w0 + u[j*5+1]*w1 + u[j*5+2]*w2
                + u[j*5+3]*w3 + u[j*5+4]*w4 + bb;
        pk.us[j] = f2bf(e);
    }
    Af[o] = pk.v;
}

// Kernel 3 (full path): NO A-build. Afrag filled by coalesced 32KB LDS copy.
// Grid (625, 2): n-dimension split in halves -> 1250 blocks, LDS 32KB ->
// 4 blocks/CU resident (launch_bounds(256,4)) = ~16 waves/CU (~50% occ,
// 2x r16). Main loop = r14's proven 76-VGPR depth-1 body, 8 iters/wave.
__global__ __launch_bounds__(256, 4) void k_main(
    const short8* __restrict__ Af, const short8* __restrict__ Bf,
    const float* __restrict__ R, const unsigned* __restrict__ Cb,
    float* __restrict__ out)
{
    __shared__ short8 Afrag[4][8][64];   // 32 KB

    const int tid  = threadIdx.x;
    const int wave = tid >> 6;
    const int l    = tid & 63;
    const int lm = l & 15;
    const int lq = l >> 4;
    const int m0 = blockIdx.x * MBLK;

    // ---- LDS fill: block's 4 m-tiles of Af are contiguous (2048 short8s) ----
    {
        const short8* afp = Af + (size_t)blockIdx.x * 2048;
        short8* ld = reinterpret_cast<short8*>(Afrag);
        #pragma unroll
        for (int i = tid; i < 2048; i += 256) ld[i] = afp[i];
    }
    __syncthreads();

    const size_t rb0 = (size_t)(m0 +  0 + lm) * NTOP;
    const size_t rb1 = (size_t)(m0 + 16 + lm) * NTOP;
    const size_t rb2 = (size_t)(m0 + 32 + lm) * NTOP;
    const size_t rb3 = (size_t)(m0 + 48 + lm) * NTOP;
    const size_t cb0 = (size_t)(m0 +  0 + lm) * 32;
    const size_t cb1 = (size_t)(m0 + 16 + lm) * 32;
    const size_t cb2 = (size_t)(m0 + 32 + lm) * 32;
    const size_t cb3 = (size_t)(m0 + 48 + lm) * 32;

    auto LOADIT = [&](int nt16_, f32x4* rv_, unsigned* cw_) {
        const int nst = (nt16_ << 4) + (lq << 2);
        if (nst < NTOP) {
            const int ws = nst >> 5;
            rv_[0] = *reinterpret_cast<const f32x4*>(R + rb0 + nst);
            rv_[1] = *reinterpret_cast<const f32x4*>(R + rb1 + nst);
            rv_[2] = *reinterpret_cast<const f32x4*>(R + rb2 + nst);
            rv_[3] = *reinterpret_cast<const f32x4*>(R + rb3 + nst);
            cw_[0] = Cb[cb0 + ws];
            cw_[1] = Cb[cb1 + ws];
            cw_[2] = Cb[cb2 + ws];
            cw_[3] = Cb[cb3 + ws];
        } else {
            #pragma unroll
            for (int q = 0; q < 4; ++q) {
                rv_[q] = (f32x4){0.f, 0.f, 0.f, 0.f};
                cw_[q] = 0u;
            }
        }
    };

    auto LOADBF = [&](int nt16_, short8* b_) {
        #pragma unroll
        for (int s = 0; s < 8; ++s)
            b_[s] = Bf[((nt16_ * 8 + s) << 6) + l];
    };

    float lpsum = 0.f;
    const int nt0 = blockIdx.y * 32 + (wave << 3);   // 8 tiles per wave

    short8 bfc[8], bfn[8];
    f32x4 rv[4]; unsigned cw[4];
    LOADBF(nt0, bfc);
    LOADIT(nt0, rv, cw);

    for (int it = 0; it < 8; ++it) {
        const int nt16 = nt0 + it;

        __builtin_amdgcn_sched_barrier(0);
        if (it < 7) LOADBF(nt16 + 1, bfn);
        __builtin_amdgcn_sched_barrier(0);

        f32x4 acc[4];
        #pragma unroll
        for (int mt = 0; mt < 4; ++mt) acc[mt] = (f32x4){0.f, 0.f, 0.f, 0.f};

        #pragma unroll
        for (int s = 0; s < 8; ++s) {
            const short8 bfr = bfc[s];
            const short8 a0 = Afrag[0][s][l];
            const short8 a1 = Afrag[1][s][l];
            const short8 a2 = Afrag[2][s][l];
            const short8 a3 = Afrag[3][s][l];
            acc[0] = __builtin_amdgcn_mfma_f32_16x16x32_bf16(bfr, a0, acc[0], 0, 0, 0);
            acc[1] = __builtin_amdgcn_mfma_f32_16x16x32_bf16(bfr, a1, acc[1], 0, 0, 0);
            acc[2] = __builtin_amdgcn_mfma_f32_16x16x32_bf16(bfr, a2, acc[2], 0, 0, 0);
            acc[3] = __builtin_amdgcn_mfma_f32_16x16x32_bf16(bfr, a3, acc[3], 0, 0, 0);
        }

        f32x4 rv2[4]; unsigned cw2[4];

        __builtin_amdgcn_sched_barrier(0);
        if (it < 7) LOADIT(nt16 + 1, rv2, cw2);
        __builtin_amdgcn_sched_barrier(0);

        const int sh = ((nt16 & 1) << 4) + (lq << 2);
        #pragma unroll
        for (int mt = 0; mt < 4; ++mt) {
            const unsigned y = cw[mt] >> sh;
            #pragma unroll
            for (int r = 0; r < 4; ++r) {
                float muv = 1.f / (1.f + __expf(-acc[mt][r]));
                float d   = rv[mt][r] - muv;
                float lp  = -50.f * d * d + 1.3836465597893728f;
                if ((y >> r) & 1u) lpsum += lp;
            }
        }

        if (it < 7) {
            #pragma unroll
            for (int s = 0; s < 8; ++s) bfc[s] = bfn[s];
            rv[0] = rv2[0]; cw[0] = cw2[0];
            rv[1] = rv2[1]; cw[1] = cw2[1];
            rv[2] = rv2[2]; cw[2] = cw2[2];
            rv[3] = rv2[3]; cw[3] = cw2[3];
        }
    }

    #pragma unroll
    for (int off = 32; off > 0; off >>= 1) lpsum += __shfl_down(lpsum, off);
    if (l == 0) atomicAdd(out, lpsum);
}

// Fallback (ws too small for Af): r16 configuration — A-build in-kernel.
__global__ __launch_bounds__(256, 3) void k_main_fb(
    const float* __restrict__ U, const float* __restrict__ w5,
    const float* __restrict__ b1, const short8* __restrict__ Bf,
    const float* __restrict__ R, const unsigned* __restrict__ Cb,
    float* __restrict__ out)
{
    __shared__ short8 Afrag[4][8][64];
    __shared__ float  rawU[4 * 1284];

    const int tid  = threadIdx.x;
    const int wave = tid >> 6;
    const int l    = tid & 63;
    const int lm = l & 15;
    const int lq = l >> 4;
    const int m0 = blockIdx.x * MBLK;

    const float w0 = w5[0], w1 = w5[1], w2 = w5[2], w3 = w5[3], w4 = w5[4];
    const float bb = b1[0];

    {
        const float* ub = U + (size_t)m0 * (KC * 5);
        float* dst0; float* dst1; float* dst2; float* dst3; float* dst4;
        {
            int i0 = 0 * 1024 + tid * 4; dst0 = &rawU[(i0 / 1280) * 1284 + i0 % 1280];
            int i1 = 1 * 1024 + tid * 4; dst1 = &rawU[(i1 / 1280) * 1284 + i1 % 1280];
            int i2 = 2 * 1024 + tid * 4; dst2 = &rawU[(i2 / 1280) * 1284 + i2 % 1280];
            int i3 = 3 * 1024 + tid * 4; dst3 = &rawU[(i3 / 1280) * 1284 + i3 % 1280];
            int i4 = 4 * 1024 + tid * 4; dst4 = &rawU[(i4 / 1280) * 1284 + i4 % 1280];
        }
        const int chunk = tid >> 1;
        const int half  = tid & 1;
        const int s_c   = chunk >> 4;
        const int lqc   = (chunk >> 2) & 3;
        const int lmh   = chunk & 3;
        const int fi    = lmh * 1284 + s_c * 160 + lqc * 40 + half * 20;

        f32x4 st0, st1, st2, st3, st4;
        st0 = *reinterpret_cast<const f32x4*>(ub + 0 * 1024 + tid * 4);
        st1 = *reinterpret_cast<const f32x4*>(ub + 1 * 1024 + tid * 4);
        st2 = *reinterpret_cast<const f32x4*>(ub + 2 * 1024 + tid * 4);
        st3 = *reinterpret_cast<const f32x4*>(ub + 3 * 1024 + tid * 4);
        st4 = *reinterpret_cast<const f32x4*>(ub + 4 * 1024 + tid * 4);

        for (int g = 0; g < 16; ++g) {
            *reinterpret_cast<f32x4*>(dst0) = st0;
            *reinterpret_cast<f32x4*>(dst1) = st1;
            *reinterpret_cast<f32x4*>(dst2) = st2;
            *reinterpret_cast<f32x4*>(dst3) = st3;
            *reinterpret_cast<f32x4*>(dst4) = st4;
            __syncthreads();
            if (g < 15) {
                const float* src = ub + (size_t)(g + 1) * 5120;
                st0 = *reinterpret_cast<const f32x4*>(src + 0 * 1024 + tid * 4);
                st1 = *reinterpret_cast<const f32x4*>(src + 1 * 1024 + tid * 4);
                st2 = *reinterpret_cast<const f32x4*>(src + 2 * 1024 + tid * 4);
                st3 = *reinterpret_cast<const f32x4*>(src + 3 * 1024 + tid * 4);
                st4 = *reinterpret_cast<const f32x4*>(src + 4 * 1024 + tid * 4);
            }
            {
                float u[20];
                #pragma unroll
                for (int i = 0; i < 5; ++i) {
                    f32x4 t = *reinterpret_cast<const f32x4*>(&rawU[fi + i * 4]);
                    u[i*4+0] = t.x; u[i*4+1] = t.y; u[i*4+2] = t.z; u[i*4+3] = t.w;
                }
                us4 pk;
                #pragma unroll
                for (int j = 0; j < 4; ++j) {
                    float e = u[j*5+0]*w0 + u[j*5+1]*w1 + u[j*5+2]*w2
                            + u[j*5+3]*w3 + u[j*5+4]*w4 + bb;
                    pk[j] = f2bf(e);
                }
                const int mt = g >> 2;
                const int ll = lqc * 16 + ((g & 3) * 4 + lmh);
                *reinterpret_cast<us4*>(
                    reinterpret_cast<unsigned short*>(&Afrag[mt][s_c][ll]) + half * 4) = pk;
            }
            __syncthreads();
        }
    }

    const size_t rb0 = (size_t)(m0 +  0 + lm) * NTOP;
    const size_t rb1 = (size_t)(m0 + 16 + lm) * NTOP;
    const size_t rb2 = (size_t)(m0 + 32 + lm) * NTOP;
    const size_t rb3 = (size_t)(m0 + 48 + lm) * NTOP;
    const size_t cb0 = (size_t)(m0 +  0 + lm) * 32;
    const size_t cb1 = (size_t)(m0 + 16 + lm) * 32;
    const size_t cb2 = (size_t)(m0 + 32 + lm) * 32;
    const size_t cb3 = (size_t)(m0 + 48 + lm) * 32;

    auto LOADIT = [&](int nt16_, f32x4* rv_, unsigned* cw_) {
        const int nst = (nt16_ << 4) + (lq << 2);
        if (nst < NTOP) {
            const int ws = nst >> 5;
            rv_[0] = *reinterpret_cast<const f32x4*>(R + rb0 + nst);
            rv_[1] = *reinterpret_cast<const f32x4*>(R + rb1 + nst);
            rv_[2] = *reinterpret_cast<const f32x4*>(R + rb2 + nst);
            rv_[3] = *reinterpret_cast<const f32x4*>(R + rb3 + nst);
            cw_[0] = Cb[cb0 + ws];
            cw_[1] = Cb[cb1 + ws];
            cw_[2] = Cb[cb2 + ws];
            cw_[3] = Cb[cb3 + ws];
        } else {
            #pragma unroll
            for (int q = 0; q < 4; ++q) {
                rv_[q] = (f32x4){0.f, 0.f, 0.f, 0.f};
                cw_[q] = 0u;
            }
        }
    };

    auto LOADBF = [&](int nt16_, short8* b_) {
        #pragma unroll
        for (int s = 0; s < 8; ++s)
            b_[s] = Bf[((nt16_ * 8 + s) << 6) + l];
    };

    float lpsum = 0.f;
    const int nt0 = wave << 4;

    short8 bfc[8], bfn[8];
    f32x4 rv[4]; unsigned cw[4];
    LOADBF(nt0, bfc);
    LOADIT(nt0, rv, cw);

    for (int it = 0; it < 16; ++it) {
        const int nt16 = nt0 + it;

        __builtin_amdgcn_sched_barrier(0);
        if (it < 15) LOADBF(nt16 + 1, bfn);
        __builtin_amdgcn_sched_barrier(0);

        f32x4 acc[4];
        #pragma unroll
        for (int mt = 0; mt < 4; ++mt) acc[mt] = (f32x4){0.f, 0.f, 0.f, 0.f};

        #pragma unroll
        for (int s = 0; s < 8; ++s) {
            const short8 bfr = bfc[s];
            const short8 a0 = Afrag[0][s][l];
            const short8 a1 = Afrag[1][s][l];
            const short8 a2 = Afrag[2][s][l];
            const short8 a3 = Afrag[3][s][l];
            acc[0] = __builtin_amdgcn_mfma_f32_16x16x32_bf16(bfr, a0, acc[0], 0, 0, 0);
            acc[1] = __builtin_amdgcn_mfma_f32_16x16x32_bf16(bfr, a1, acc[1], 0, 0, 0);
            acc[2] = __builtin_amdgcn_mfma_f32_16x16x32_bf16(bfr, a2, acc[2], 0, 0, 0);
            acc[3] = __builtin_amdgcn_mfma_f32_16x16x32_bf16(bfr, a3, acc[3], 0, 0, 0);
        }

        f32x4 rv2[4]; unsigned cw2[4];

        __builtin_amdgcn_sched_barrier(0);
        if (it < 15) LOADIT(nt16 + 1, rv2, cw2);
        __builtin_amdgcn_sched_barrier(0);

        const int sh = ((nt16 & 1) << 4) + (lq << 2);
        #pragma unroll
        for (int mt = 0; mt < 4; ++mt) {
            const unsigned y = cw[mt] >> sh;
            #pragma unroll
            for (int r = 0; r < 4; ++r) {
                float muv = 1.f / (1.f + __expf(-acc[mt][r]));
                float d   = rv[mt][r] - muv;
                float lp  = -50.f * d * d + 1.3836465597893728f;
                if ((y >> r) & 1u) lpsum += lp;
            }
        }

        if (it < 15) {
            #pragma unroll
            for (int s = 0; s < 8; ++s) bfc[s] = bfn[s];
            rv[0] = rv2[0]; cw[0] = cw2[0];
            rv[1] = rv2[1]; cw[1] = cw2[1];
            rv[2] = rv2[2]; cw[2] = cw2[2];
            rv[3] = rv2[3]; cw[3] = cw2[3];
        }
    }

    #pragma unroll
    for (int off = 32; off > 0; off >>= 1) lpsum += __shfl_down(lpsum, off);
    if (l == 0) atomicAdd(out, lpsum);
}

extern "C" void kernel_launch(void* const* d_in, const int* in_sizes, int n_in,
                              void* d_out, int out_size, void* d_ws, size_t ws_size,
                              hipStream_t stream) {
    const float* V     = (const float*)d_in[1];
    const float* R     = (const float*)d_in[2];
    const float* nw    = (const float*)d_in[3];
    const float* U     = (const float*)d_in[4];
    const float* w5    = (const float*)d_in[5];
    const float* b1    = (const float*)d_in[6];
    const float* noise = (const float*)d_in[7];
    const int*   C     = (const int*)d_in[8];
    float* out = (float*)d_out;

    float*          colsum = (float*)d_ws;
    unsigned short* Bp     = (unsigned short*)((char*)d_ws + OFF_BP);
    unsigned*       Cb     = (unsigned*)((char*)d_ws + OFF_CB);
    short8*         Af     = (short8*)((char*)d_ws + OFF_AF);

    hipMemsetAsync(colsum, 0, NTOP * sizeof(float), stream);
    hipMemsetAsync(out, 0, sizeof(float), stream);
    hipLaunchKernelGGL(k_prep, dim3(4, 125), dim3(256), 0, stream, nw, colsum);
    hipLaunchKernelGGL(k_vj, dim3(128), dim3(256), 0, stream,
                       V, noise, colsum, Bp);
    hipLaunchKernelGGL(k_cmask, dim3(5000), dim3(256), 0, stream, C, Cb);

    if (ws_size >= (size_t)WS_FULL) {
        hipLaunchKernelGGL(k_uemb, dim3(5000), dim3(256), 0, stream,
                           U, w5, b1, Af);
        hipLaunchKernelGGL(k_main, dim3(MROWS / MBLK, 2), dim3(256), 0, stream,
                           Af, (const short8*)Bp, R, Cb, out);
    } else {
        hipLaunchKernelGGL(k_main_fb, dim3(MROWS / MBLK), dim3(256), 0, stream,
                           U, w5, b1, (const short8*)Bp, R, Cb, out);
    }
}